// Round 7
// baseline (190.807 us; speedup 1.0000x reference)
//
#include <hip/hip_runtime.h>
#include <stdint.h>

#define Bb 8
#define Dd 256
#define Ll 4096
#define Kk 4096
#define Nn (Bb * Ll)          // 32768 rows
#define OUT0 (Bb * Dd * Ll)   // 8388608

typedef int    int4v   __attribute__((ext_vector_type(4)));
typedef int    int8v   __attribute__((ext_vector_type(8)));
typedef float  floatx4 __attribute__((ext_vector_type(4)));

#define SCALE1 0x7F7F7F7F     // E8M0 exp=127 -> x1.0 for every 32-elem block

union V8 { int8v v; int4v h[2]; };

__device__ __forceinline__ void async_load16(const void* g, void* l) {
    __builtin_amdgcn_global_load_lds((const __attribute__((address_space(1))) void*)g,
                                     (__attribute__((address_space(3))) void*)l, 16, 0, 0);
}

// ---------------------------------------------------------------- kernel 1
// normalize codebook rows, scale x16, cast fp8 e4m3, row-major wn[k][d].
// Block 0 zeroes counts + lossacc + done.
__global__ void k_prep(const float* __restrict__ w, unsigned char* __restrict__ wn,
                       int* __restrict__ counts) {
    int blk = blockIdx.x, tid = threadIdx.x;
    if (blk == 0)
        for (int i = tid; i < Kk + 2; i += 256) counts[i] = 0;
    int row  = blk * 4 + (tid >> 6);
    int lane = tid & 63;
    float4 v = ((const float4*)(w + (size_t)row * Dd))[lane];
    float ss = v.x*v.x + v.y*v.y + v.z*v.z + v.w*v.w;
#pragma unroll
    for (int m = 1; m < 64; m <<= 1) ss += __shfl_xor(ss, m, 64);
    float s = 16.0f / fmaxf(sqrtf(ss), 1e-12f);
    int p = __builtin_amdgcn_cvt_pk_fp8_f32(v.x * s, v.y * s, 0, false);
    p     = __builtin_amdgcn_cvt_pk_fp8_f32(v.z * s, v.w * s, p, true);
    ((int*)(wn + (size_t)row * Dd))[lane] = p;
}

// ---------------------------------------------------------------- kernel 2
// transpose + fp8 cast + full-col argmax GEMM (epilogue split off this
// round for ablation-by-decomposition). REG-PIPELINED inner loop: B
// fragment double-buffered in REGISTERS so iteration t's MFMAs (regs read
// at t-1) overlap t+1's ds_read + t+2's DMA issue. The wave's only waits
// are on ops issued a full iteration (~500cyc) earlier -> L2 latency
// covered, MFMA near-continuous. R1-R6 post-mortem: every structure with
// the wait BETWEEN ds_read and same-tile MFMA pinned MfmaUtil at 13-17%
// (per-wave iteration serialization + L2 convoy), barriers or not.
// Wave-private 3-buffer LDS strips (16 cols x 256B): DMA at t targets
// buf (t+2)%3 = strip t-1's buffer, whose ds_reads completed before
// t-1's MFMAs (compiler register-tracked lgkmcnt) -> no hazard, no sync.
// 512 blocks x 256 thr, 64 rows x 4096 cols; XCD swizzle: XCD owns batch.
__global__ __launch_bounds__(256, 2) void k_gemm(
        const float* __restrict__ x, const unsigned char* __restrict__ Wn,
        int* __restrict__ idxout, int* __restrict__ counts) {
    __shared__ __align__(16) unsigned char As[64 * 256];        // 16 KB
    __shared__ __align__(16) unsigned char Bs[4][3][16 * 256];  // 48 KB
    __shared__ unsigned int red[64][4];

    int bid = blockIdx.x;
    int bm = ((bid & 7) << 6) | (bid >> 3);   // XCD j -> orig 64j..64j+63
    int tid = threadIdx.x, lane = tid & 63, wv = tid >> 6;
    int l15 = lane & 15, l4 = lane >> 4;

    // per-lane DMA maps for one strip (16 rows x 256B, 4 wave-loads):
    // LDS chunk q = j*64+lane holds global chunk (c=q>>4, p=(q&15)^(c&15))
    int goff[4], loff[4];
#pragma unroll
    for (int j = 0; j < 4; ++j) {
        int c = j * 4 + l4;
        goff[j] = c * 256 + ((l15 ^ (c & 15)) << 4);
        loff[j] = j * 1024 + lane * 16;
    }

    // prologue: stage strips 0,1 into bufs 0,1 (transpose sync drains)
#pragma unroll
    for (int j = 0; j < 4; ++j)
        async_load16(Wn + (size_t)(0 * 4 + wv) * 4096 + goff[j],
                     Bs[wv][0] + loff[j]);
#pragma unroll
    for (int j = 0; j < 4; ++j)
        async_load16(Wn + (size_t)(1 * 4 + wv) * 4096 + goff[j],
                     Bs[wv][1] + loff[j]);

    // ---- fused transpose: x slab [256 d][64 l] f32 -> As[l][d] fp8 (swz)
    int b = bm >> 6, l0 = (bm & 63) * 64;
    const float* xs = x + (size_t)b * Dd * Ll + l0;
    int lg = tid & 15, dgr = tid >> 4;    // 16 l-groups x 16 d-groups
#pragma unroll
    for (int i = 0; i < 4; ++i) {
        int d0 = dgr * 4 + i * 64;
        const float* s0 = xs + (size_t)d0 * Ll + lg * 4;
        float4 f0 = *(const float4*)(s0);
        float4 f1 = *(const float4*)(s0 + Ll);
        float4 f2 = *(const float4*)(s0 + 2 * (size_t)Ll);
        float4 f3 = *(const float4*)(s0 + 3 * (size_t)Ll);
#pragma unroll
        for (int jl = 0; jl < 4; ++jl) {
            float a0 = ((const float*)&f0)[jl], a1 = ((const float*)&f1)[jl];
            float a2 = ((const float*)&f2)[jl], a3 = ((const float*)&f3)[jl];
            int pk = __builtin_amdgcn_cvt_pk_fp8_f32(a0, a1, 0, false);
            pk     = __builtin_amdgcn_cvt_pk_fp8_f32(a2, a3, pk, true);
            int l = lg * 4 + jl;
            *(int*)(As + l * 256 + (((d0 >> 4) ^ (l & 15)) << 4) + (d0 & 15)) = pk;
        }
    }
    __syncthreads();   // As complete + strips 0,1 DMA drained (vmcnt 0 here)

    // ---- A fragments (64 VGPRs): row = fm*16+l15, k = ks*128+l4*32
    int8v af[4][2];
#pragma unroll
    for (int fm = 0; fm < 4; ++fm)
#pragma unroll
        for (int ks = 0; ks < 2; ++ks) {
            int l = fm * 16 + l15;
            int ch = ks * 8 + l4 * 2;
            V8 u;
            u.h[0] = *(const int4v*)(As + l * 256 + ((ch ^ l15) << 4));
            u.h[1] = *(const int4v*)(As + l * 256 + (((ch + 1) ^ l15) << 4));
            af[fm][ks] = u.v;
        }

    unsigned int rk[4][4];
#pragma unroll
    for (int fm = 0; fm < 4; ++fm)
#pragma unroll
        for (int r = 0; r < 4; ++r) rk[fm][r] = 0u;

    int base0 = l15 * 256;
#define DSRD(D0, D1, P)                                                       \
    do {                                                                      \
        const unsigned char* pp_ = (P);                                       \
        D0.h[0] = *(const int4v*)(pp_ + base0 + (((l4 * 2 + 0) ^ l15) << 4)); \
        D0.h[1] = *(const int4v*)(pp_ + base0 + (((l4 * 2 + 1) ^ l15) << 4)); \
        D1.h[0] = *(const int4v*)(pp_ + base0 + (((8 + l4 * 2) ^ l15) << 4)); \
        D1.h[1] = *(const int4v*)(pp_ + base0 + (((9 + l4 * 2) ^ l15) << 4)); \
    } while (0)

    V8 bfA0, bfA1, bfB0, bfB1;
    DSRD(bfA0, bfA1, Bs[wv][0]);   // strip 0 -> regs (staged, drained)

    // ---- main loop: per iteration t: wait strip t+1 (issued t-1, ~500cyc
    // slack); issue DMA strip t+2; ds_read strip t+1 -> bfB; MFMA on bfA
    // (read last iter; lgkmcnt inserted by compiler register tracking);
    // keypack; swap. No barriers, no sched fences between ds_read and MFMA.
#pragma unroll 2
    for (int t = 0; t < 64; ++t) {
        asm volatile("s_waitcnt vmcnt(0)" ::: "memory");   // strip t+1 ready
        if (t < 62) {
            const unsigned char* g = Wn + (size_t)((t + 2) * 4 + wv) * 4096;
            unsigned char* lb = Bs[wv][(t + 2) % 3];
#pragma unroll
            for (int j = 0; j < 4; ++j)
                async_load16(g + goff[j], lb + loff[j]);
        }
        if (t < 63) DSRD(bfB0, bfB1, Bs[wv][(t + 1) % 3]);
        __builtin_amdgcn_s_setprio(1);
        floatx4 acc[4];
#pragma unroll
        for (int fm = 0; fm < 4; ++fm) {
            floatx4 a = (floatx4)512.0f;      // bias -> positive, int-ordered
            a = __builtin_amdgcn_mfma_scale_f32_16x16x128_f8f6f4(
                    af[fm][0], bfA0.v, a, 0, 0, 0, SCALE1, 0, SCALE1);
            a = __builtin_amdgcn_mfma_scale_f32_16x16x128_f8f6f4(
                    af[fm][1], bfA1.v, a, 0, 0, 0, SCALE1, 0, SCALE1);
            acc[fm] = a;
        }
        __builtin_amdgcn_s_setprio(0);
        unsigned int i0 = (unsigned)((t * 4 + wv) * 16 + l15);
#pragma unroll
        for (int fm = 0; fm < 4; ++fm)
#pragma unroll
            for (int r = 0; r < 4; ++r) {
                unsigned int k0 = (__float_as_uint(acc[fm][r]) & 0xFFFFF000u) | i0;
                rk[fm][r] = rk[fm][r] > k0 ? rk[fm][r] : k0;
            }
        bfA0 = bfB0; bfA1 = bfB1;
    }
#undef DSRD

    // epilogue: key-max across 16 col-lanes, then across 4 wave-strips
#pragma unroll
    for (int fm = 0; fm < 4; ++fm)
#pragma unroll
        for (int r = 0; r < 4; ++r) {
            unsigned int kx = rk[fm][r];
#pragma unroll
            for (int md = 1; md <= 8; md <<= 1) {
                unsigned int o = (unsigned int)__shfl_xor((int)kx, md, 64);
                kx = kx > o ? kx : o;
            }
            if (l15 == 0) red[fm * 16 + l4 * 4 + r][wv] = kx;
        }
    __syncthreads();
    if (tid < 64) {
        unsigned int k0 = red[tid][0], k1 = red[tid][1];
        unsigned int k2 = red[tid][2], k3 = red[tid][3];
        unsigned int kx = k0 > k1 ? k0 : k1;
        kx = kx > k2 ? kx : k2;
        kx = kx > k3 ? kx : k3;
        int ix = (int)(kx & 0xFFFu);
        idxout[bm * 64 + tid] = ix;
        atomicAdd(&counts[ix], 1);
    }
}

// ---------------------------------------------------------------- kernel 3
// standalone gather + out + loss (split for ablation; register-only gather,
// no LDS staging -> no bank conflicts). 1024 blocks x 256 thr (4/CU) for
// latency hiding; 16 independent float4 loads in flight per thread.
// Block: 32 rows x 256 d. Last block computes loss + perplexity scalars.
__global__ __launch_bounds__(256) void k_epi(
        const float* __restrict__ x, const float* __restrict__ w,
        const int* __restrict__ idx, float* __restrict__ out,
        int* __restrict__ counts) {
    __shared__ int kidx[32];
    __shared__ float wsum[4];
    __shared__ int lastp;

    float* lossacc = (float*)(counts + Kk);
    int*   done    = counts + Kk + 1;

    int bid = blockIdx.x;
    int bm = ((bid & 7) << 7) | (bid >> 3);   // 1024 = 8 XCD x 128, bijective
    int tid = threadIdx.x, lane = tid & 63, wv = tid >> 6;
    int b = bm >> 7, l0 = (bm & 127) * 32;
    if (tid < 32) kidx[tid] = idx[bm * 32 + tid];
    __syncthreads();

    int lg = tid & 7, dgr = tid >> 3;    // 8 l-groups(x4 l) x 32 d-groups(x8 d)
    const float* xs = x + (size_t)b * Dd * Ll + l0;
    float*       os = out + (size_t)b * Dd * Ll + l0;
    int r0 = lg * 4, d0 = dgr * 8;

    float4 xv[8], q4[4][2];
#pragma unroll
    for (int dd = 0; dd < 8; ++dd)
        xv[dd] = *(const float4*)(xs + (size_t)(d0 + dd) * Ll + lg * 4);
#pragma unroll
    for (int jl = 0; jl < 4; ++jl) {
        const float* wr = w + (size_t)kidx[r0 + jl] * Dd + d0;
        q4[jl][0] = *(const float4*)(wr);
        q4[jl][1] = *(const float4*)(wr + 4);
    }
    float ls = 0.f;
#pragma unroll
    for (int dd = 0; dd < 8; ++dd) {
        int h = dd >> 2, c = dd & 3;
        float4 qq;
        qq.x = ((const float*)&q4[0][h])[c];
        qq.y = ((const float*)&q4[1][h])[c];
        qq.z = ((const float*)&q4[2][h])[c];
        qq.w = ((const float*)&q4[3][h])[c];
        float e0 = qq.x - xv[dd].x, e1 = qq.y - xv[dd].y;
        float e2 = qq.z - xv[dd].z, e3 = qq.w - xv[dd].w;
        ls += e0*e0 + e1*e1 + e2*e2 + e3*e3;
        *(float4*)(os + (size_t)(d0 + dd) * Ll + lg * 4) = qq;
    }

#pragma unroll
    for (int m = 1; m < 64; m <<= 1) ls += __shfl_xor(ls, m, 64);
    if (lane == 0) wsum[wv] = ls;
    __syncthreads();
    if (tid == 0) {
        atomicAdd(lossacc, wsum[0] + wsum[1] + wsum[2] + wsum[3]);
        __threadfence();
        lastp = (atomicAdd(done, 1) == 1023);
    }
    __syncthreads();
    if (lastp) {                  // all counts (k_gemm) + loss atomics visible
        __threadfence();
        float s = 0.f;
        for (int i = tid; i < Kk; i += 256) {
            float p = (float)counts[i] * (1.0f / Nn);
            s += p * logf(p + 1e-10f);
        }
#pragma unroll
        for (int m = 1; m < 64; m <<= 1) s += __shfl_xor(s, m, 64);
        if (lane == 0) wsum[wv] = s;
        __syncthreads();
        if (tid == 0) {
            out[OUT0]     = lossacc[0] * 1.25f / (float)OUT0;  // q + 0.25*e latent
            out[OUT0 + 1] = expf(-(wsum[0] + wsum[1] + wsum[2] + wsum[3]));
        }
    }
}

// ---------------------------------------------------------------- launch
extern "C" void kernel_launch(void* const* d_in, const int* in_sizes, int n_in,
                              void* d_out, int out_size, void* d_ws, size_t ws_size,
                              hipStream_t stream) {
    const float* x = (const float*)d_in[0];   // [B, D, L]
    const float* w = (const float*)d_in[1];   // [K, D]
    float* out = (float*)d_out;
    char* ws = (char*)d_ws;

    unsigned char* wn     = (unsigned char*)ws;                      // 1 MB fp8
    int*           counts = (int*)(ws + (1u << 20));                 // 16 KB + 8 B
    int*           idxb   = (int*)(ws + (1u << 20) + (32u << 10));   // 128 KB

    k_prep<<<1024, 256, 0, stream>>>(w, wn, counts);
    k_gemm<<<512,  256, 0, stream>>>(x, wn, idxb, counts);
    k_epi <<<1024, 256, 0, stream>>>(x, w, idxb, out, counts);
}

// Round 8
// 152.338 us; speedup vs baseline: 1.2525x; 1.2525x over previous
//
#include <hip/hip_runtime.h>
#include <stdint.h>

#define Bb 8
#define Dd 256
#define Ll 4096
#define Kk 4096
#define Nn (Bb * Ll)          // 32768 rows
#define OUT0 (Bb * Dd * Ll)   // 8388608

typedef int    int4v   __attribute__((ext_vector_type(4)));
typedef int    int8v   __attribute__((ext_vector_type(8)));
typedef float  floatx4 __attribute__((ext_vector_type(4)));

#define SCALE1 0x7F7F7F7F     // E8M0 exp=127 -> x1.0 for every 32-elem block

union V8 { int8v v; int4v h[2]; };

__device__ __forceinline__ void async_load16(const void* g, void* l) {
    __builtin_amdgcn_global_load_lds((const __attribute__((address_space(1))) void*)g,
                                     (__attribute__((address_space(3))) void*)l, 16, 0, 0);
}

// ---------------------------------------------------------------- kernel 1
// normalize codebook rows, scale x16, cast fp8 e4m3, row-major wn[k][d].
// Block 0 zeroes counts + lossacc + done.
__global__ void k_prep(const float* __restrict__ w, unsigned char* __restrict__ wn,
                       int* __restrict__ counts) {
    int blk = blockIdx.x, tid = threadIdx.x;
    if (blk == 0)
        for (int i = tid; i < Kk + 2; i += 256) counts[i] = 0;
    int row  = blk * 4 + (tid >> 6);
    int lane = tid & 63;
    float4 v = ((const float4*)(w + (size_t)row * Dd))[lane];
    float ss = v.x*v.x + v.y*v.y + v.z*v.z + v.w*v.w;
#pragma unroll
    for (int m = 1; m < 64; m <<= 1) ss += __shfl_xor(ss, m, 64);
    float s = 16.0f / fmaxf(sqrtf(ss), 1e-12f);
    int p = __builtin_amdgcn_cvt_pk_fp8_f32(v.x * s, v.y * s, 0, false);
    p     = __builtin_amdgcn_cvt_pk_fp8_f32(v.z * s, v.w * s, p, true);
    ((int*)(wn + (size_t)row * Dd))[lane] = p;
}

// ---------------------------------------------------------------- kernel 2
// fused transpose + fp8 argmax-GEMM + gather/loss epilogue (2-kernel total:
// R7 showed each standalone kernel costs ~30us of ramp; R7 also proved the
// reg-pipelined loop = 62us vs 95 barriered, with VALUBusy 34% > MfmaUtil
// 20% -> loop is now VALU/latency-limited, not sync-limited).
// R8 loop changes (on the proven R7 wave-private structure):
//  * period-6 hand schedule (3 bufs x fA/fB ping-pong): no %3 math, no
//    bfA=bfB v_mov swaps.
//  * 2 strips in flight, wait vmcnt(4): DMA waited at top of step T was
//    issued at step T-2 (~400cyc) -> L2 latency covered (R7 had 1 strip,
//    vmcnt(0) on a ~200cyc-old DMA -> ~100cyc naked stall per iter).
//  * lgkmcnt(0) before each DMA (hidden under MFMA): makes the 3-buffer
//    LDS reuse provably race-free (DMA T+3 targets strip T's buffer,
//    whose ds_reads completed at the previous step's lgkm wait).
//  * v_bfi_b32 keypack: (bits&M)|i0 in one op -> 2 VALU/candidate not 3.
// 512 blocks x 256 thr, 64 rows x all 4096 cols; wave wv owns 16-col strip
// g=t*4+wv. XCD swizzle: each XCD owns one batch b; bijective (512%8==0).
__global__ __launch_bounds__(256, 2) void k_fused(
        const float* __restrict__ x, const unsigned char* __restrict__ Wn,
        const float* __restrict__ w, float* __restrict__ out,
        int* __restrict__ counts) {
    __shared__ __align__(16) unsigned char As[64 * 256];        // 16 KB
    __shared__ __align__(16) unsigned char Bs[4][3][16 * 256];  // 48 KB
    __shared__ unsigned int red[64][4];
    __shared__ int kidx[64];
    __shared__ float wsum[4];
    __shared__ int lastp;

    float* lossacc = (float*)(counts + Kk);
    int*   done    = counts + Kk + 1;

    int bid = blockIdx.x;
    int bm = ((bid & 7) << 6) | (bid >> 3);   // XCD j -> orig 64j..64j+63
    int tid = threadIdx.x, lane = tid & 63, wv = tid >> 6;
    int l15 = lane & 15, l4 = lane >> 4;

    // per-lane DMA maps for one strip (16 rows x 256B, 4 wave-loads)
    int goff[4], loff[4];
#pragma unroll
    for (int j = 0; j < 4; ++j) {
        int c = j * 4 + l4;
        goff[j] = c * 256 + ((l15 ^ (c & 15)) << 4);
        loff[j] = j * 1024 + lane * 16;
    }
    // per-lane ds_read addrs within a strip (loop-invariant)
    int dsa[4];
    dsa[0] = l15 * 256 + (((l4 * 2 + 0) ^ l15) << 4);
    dsa[1] = l15 * 256 + (((l4 * 2 + 1) ^ l15) << 4);
    dsa[2] = l15 * 256 + (((8 + l4 * 2) ^ l15) << 4);
    dsa[3] = l15 * 256 + (((9 + l4 * 2) ^ l15) << 4);

    // prologue: stage strips 0,1,2 into bufs 0,1,2 (transpose sync drains)
#pragma unroll
    for (int s = 0; s < 3; ++s)
#pragma unroll
        for (int j = 0; j < 4; ++j)
            async_load16(Wn + (size_t)(s * 4 + wv) * 4096 + goff[j],
                         Bs[wv][s] + loff[j]);

    // ---- fused transpose: x slab [256 d][64 l] f32 -> As[l][d] fp8 (swz)
    int b = bm >> 6, l0 = (bm & 63) * 64;
    const float* xs = x + (size_t)b * Dd * Ll + l0;
    int lg = tid & 15, dgr = tid >> 4;    // 16 l-groups x 16 d-groups
#pragma unroll
    for (int i = 0; i < 4; ++i) {
        int d0 = dgr * 4 + i * 64;
        const float* s0 = xs + (size_t)d0 * Ll + lg * 4;
        float4 f0 = *(const float4*)(s0);
        float4 f1 = *(const float4*)(s0 + Ll);
        float4 f2 = *(const float4*)(s0 + 2 * (size_t)Ll);
        float4 f3 = *(const float4*)(s0 + 3 * (size_t)Ll);
#pragma unroll
        for (int jl = 0; jl < 4; ++jl) {
            float a0 = ((const float*)&f0)[jl], a1 = ((const float*)&f1)[jl];
            float a2 = ((const float*)&f2)[jl], a3 = ((const float*)&f3)[jl];
            int pk = __builtin_amdgcn_cvt_pk_fp8_f32(a0, a1, 0, false);
            pk     = __builtin_amdgcn_cvt_pk_fp8_f32(a2, a3, pk, true);
            int l = lg * 4 + jl;
            *(int*)(As + l * 256 + (((d0 >> 4) ^ (l & 15)) << 4) + (d0 & 15)) = pk;
        }
    }
    __syncthreads();   // As complete + strips 0,1,2 DMA drained (vmcnt=0)

    // ---- A fragments (64 VGPRs): row = fm*16+l15, k = ks*128+l4*32
    int8v af[4][2];
#pragma unroll
    for (int fm = 0; fm < 4; ++fm)
#pragma unroll
        for (int ks = 0; ks < 2; ++ks) {
            int l = fm * 16 + l15;
            int ch = ks * 8 + l4 * 2;
            V8 u;
            u.h[0] = *(const int4v*)(As + l * 256 + ((ch ^ l15) << 4));
            u.h[1] = *(const int4v*)(As + l * 256 + (((ch + 1) ^ l15) << 4));
            af[fm][ks] = u.v;
        }

    unsigned int rk[4][4];
#pragma unroll
    for (int fm = 0; fm < 4; ++fm)
#pragma unroll
        for (int r = 0; r < 4; ++r) rk[fm][r] = 0u;

    unsigned int msk = 0xFFFFF000u;           // forced into VGPR by asm use
    unsigned int i0b = (unsigned)(wv * 16 + l15);

    V8 fA[2], fB[2];
    {   // pre-loop: strip 0 -> fA
        const unsigned char* pp = Bs[wv][0];
        fA[0].h[0] = *(const int4v*)(pp + dsa[0]);
        fA[0].h[1] = *(const int4v*)(pp + dsa[1]);
        fA[1].h[0] = *(const int4v*)(pp + dsa[2]);
        fA[1].h[1] = *(const int4v*)(pp + dsa[3]);
    }

    // STEP(T): wait vmcnt (strip T+1 landed; T+2 stays in flight);
    // ds_read strip T+1 -> FR; MFMA strip T on FM + bfi-keypack;
    // lgkm(0) (hidden under MFMA); DMA strip T+3 -> buf[T%3].
#define STEP(T, RB, WB, FR, FM, VMC, DODMA, DOREAD)                           \
    do {                                                                      \
        asm volatile("s_waitcnt vmcnt(" #VMC ")" ::: "memory");               \
        __builtin_amdgcn_sched_barrier(0);                                    \
        if (DOREAD) {                                                         \
            const unsigned char* pp_ = Bs[wv][RB];                            \
            FR[0].h[0] = *(const int4v*)(pp_ + dsa[0]);                       \
            FR[0].h[1] = *(const int4v*)(pp_ + dsa[1]);                       \
            FR[1].h[0] = *(const int4v*)(pp_ + dsa[2]);                       \
            FR[1].h[1] = *(const int4v*)(pp_ + dsa[3]);                       \
        }                                                                     \
        __builtin_amdgcn_s_setprio(1);                                        \
        floatx4 acc[4];                                                       \
        _Pragma("unroll")                                                     \
        for (int fm = 0; fm < 4; ++fm) {                                      \
            floatx4 a = (floatx4)512.0f;                                      \
            a = __builtin_amdgcn_mfma_scale_f32_16x16x128_f8f6f4(             \
                    af[fm][0], FM[0].v, a, 0, 0, 0, SCALE1, 0, SCALE1);       \
            a = __builtin_amdgcn_mfma_scale_f32_16x16x128_f8f6f4(             \
                    af[fm][1], FM[1].v, a, 0, 0, 0, SCALE1, 0, SCALE1);       \
            acc[fm] = a;                                                      \
        }                                                                     \
        __builtin_amdgcn_s_setprio(0);                                        \
        unsigned int i0v = i0b + (unsigned)(T) * 64u;                         \
        _Pragma("unroll")                                                     \
        for (int fm = 0; fm < 4; ++fm)                                        \
            _Pragma("unroll")                                                 \
            for (int r = 0; r < 4; ++r) {                                     \
                unsigned int kk;                                              \
                asm("v_bfi_b32 %0, %1, %2, %3"                                \
                    : "=v"(kk)                                                \
                    : "v"(msk), "v"(__float_as_uint(acc[fm][r])), "v"(i0v));  \
                rk[fm][r] = rk[fm][r] > kk ? rk[fm][r] : kk;                  \
            }                                                                 \
        if (DODMA) {                                                          \
            asm volatile("s_waitcnt lgkmcnt(0)" ::: "memory");                \
            __builtin_amdgcn_sched_barrier(0);                                \
            const unsigned char* g =                                          \
                Wn + (size_t)(((T) + 3) * 4 + wv) * 4096;                     \
            unsigned char* lb = Bs[wv][WB];                                   \
            _Pragma("unroll")                                                 \
            for (int j = 0; j < 4; ++j)                                       \
                async_load16(g + goff[j], lb + loff[j]);                      \
        }                                                                     \
    } while (0)

    for (int tb = 0; tb < 60; tb += 6) {
        STEP(tb + 0, 1, 0, fB, fA, 4, 1, 1);
        STEP(tb + 1, 2, 1, fA, fB, 4, 1, 1);
        STEP(tb + 2, 0, 2, fB, fA, 4, 1, 1);
        STEP(tb + 3, 1, 0, fA, fB, 4, 1, 1);
        STEP(tb + 4, 2, 1, fB, fA, 4, 1, 1);
        STEP(tb + 5, 0, 2, fA, fB, 4, 1, 1);
    }
    STEP(60, 1, 0, fB, fA, 4, 1, 1);   // DMA strip 63
    STEP(61, 2, 0, fA, fB, 4, 0, 1);   // no DMA (strip 64 doesn't exist)
    STEP(62, 0, 0, fB, fA, 0, 0, 1);   // drain: strip 63 ready
    STEP(63, 0, 0, fA, fB, 0, 0, 0);   // last MFMA (fB = strip 63)
#undef STEP

    // epilogue: key-max across 16 col-lanes, then across 4 wave-strips
#pragma unroll
    for (int fm = 0; fm < 4; ++fm)
#pragma unroll
        for (int r = 0; r < 4; ++r) {
            unsigned int kx = rk[fm][r];
#pragma unroll
            for (int md = 1; md <= 8; md <<= 1) {
                unsigned int o = (unsigned int)__shfl_xor((int)kx, md, 64);
                kx = kx > o ? kx : o;
            }
            if (l15 == 0) red[fm * 16 + l4 * 4 + r][wv] = kx;
        }
    __syncthreads();
    if (tid < 64) {
        unsigned int k0 = red[tid][0], k1 = red[tid][1];
        unsigned int k2 = red[tid][2], k3 = red[tid][3];
        unsigned int kx = k0 > k1 ? k0 : k1;
        kx = kx > k2 ? kx : k2;
        kx = kx > k3 ? kx : k3;
        int ix = (int)(kx & 0xFFFu);
        kidx[tid] = ix;
        atomicAdd(&counts[ix], 1);
    }
    __syncthreads();   // kidx visible to all

    // ---- fused gather + out-write + loss, registers only (R6, proven).
    // Thread (lg,dgr): l = lg*4..+3, d = dgr*4+i*64+dd. x re-read L2-warm
    // (same bytes as transpose, own-XCD via batch swizzle); w rows read in
    // contiguous 256B per 16-thread dgr-group (w 4MB, L2/L3-resident).
    float ls = 0.f;
    {
        float* os = out + (size_t)b * Dd * Ll + l0;
        int r0 = lg * 4;
#pragma unroll
        for (int i = 0; i < 4; ++i) {
            int d0 = dgr * 4 + i * 64;
            float4 xv[4];
#pragma unroll
            for (int dd = 0; dd < 4; ++dd)
                xv[dd] = *(const float4*)(xs + (size_t)(d0 + dd) * Ll + lg * 4);
            float4 q4[4];
#pragma unroll
            for (int jl = 0; jl < 4; ++jl)
                q4[jl] = *(const float4*)(w + (size_t)kidx[r0 + jl] * Dd + d0);
#pragma unroll
            for (int dd = 0; dd < 4; ++dd) {
                float4 qq;
                qq.x = ((const float*)&q4[0])[dd];
                qq.y = ((const float*)&q4[1])[dd];
                qq.z = ((const float*)&q4[2])[dd];
                qq.w = ((const float*)&q4[3])[dd];
                float e0 = qq.x - xv[dd].x, e1 = qq.y - xv[dd].y;
                float e2 = qq.z - xv[dd].z, e3 = qq.w - xv[dd].w;
                ls += e0*e0 + e1*e1 + e2*e2 + e3*e3;
                *(float4*)(os + (size_t)(d0 + dd) * Ll + lg * 4) = qq;
            }
        }
    }

#pragma unroll
    for (int m = 1; m < 64; m <<= 1) ls += __shfl_xor(ls, m, 64);
    if (lane == 0) wsum[wv] = ls;
    __syncthreads();
    if (tid == 0) {
        atomicAdd(lossacc, wsum[0] + wsum[1] + wsum[2] + wsum[3]);
        __threadfence();
        lastp = (atomicAdd(done, 1) == 511);
    }
    __syncthreads();
    if (lastp) {                  // all blocks' counts/loss atomics visible
        __threadfence();
        float s = 0.f;
        for (int i = tid; i < Kk; i += 256) {
            float p = (float)counts[i] * (1.0f / Nn);
            s += p * logf(p + 1e-10f);
        }
#pragma unroll
        for (int m = 1; m < 64; m <<= 1) s += __shfl_xor(s, m, 64);
        if (lane == 0) wsum[wv] = s;
        __syncthreads();
        if (tid == 0) {
            out[OUT0]     = lossacc[0] * 1.25f / (float)OUT0;  // q + 0.25*e latent
            out[OUT0 + 1] = expf(-(wsum[0] + wsum[1] + wsum[2] + wsum[3]));
        }
    }
}

// ---------------------------------------------------------------- launch
extern "C" void kernel_launch(void* const* d_in, const int* in_sizes, int n_in,
                              void* d_out, int out_size, void* d_ws, size_t ws_size,
                              hipStream_t stream) {
    const float* x = (const float*)d_in[0];   // [B, D, L]
    const float* w = (const float*)d_in[1];   // [K, D]
    float* out = (float*)d_out;
    char* ws = (char*)d_ws;

    unsigned char* wn     = (unsigned char*)ws;            // 1 MB fp8
    int*           counts = (int*)(ws + (1u << 20));       // 16 KB + 8 B

    k_prep <<<1024, 256, 0, stream>>>(w, wn, counts);
    k_fused<<<512,  256, 0, stream>>>(x, wn, w, out, counts);
}